// Round 3
// baseline (1737.009 us; speedup 1.0000x reference)
//
#include <hip/hip_runtime.h>
#include <math.h>

#define P_TOTAL 147456
#define HW 9216
#define CHW (512*9216)

__device__ __forceinline__ unsigned f2key(float f) {
    unsigned u = __float_as_uint(f);
    return (u & 0x80000000u) ? ~u : (u | 0x80000000u);
}

// ---------- K0: pack protos to [side][c][64] and init pwork copy ----------
__global__ void k_init(const float* __restrict__ fg, const float* __restrict__ bg,
                       float* __restrict__ protoT, float* __restrict__ pwork) {
    int i = blockIdx.x * 256 + threadIdx.x;   // 0..65535
    int side = i >> 15;
    int r = i & 32767;
    int k = r >> 9;
    int c = r & 511;
    float v = (side ? bg : fg)[k * 512 + c];
    protoT[side * 32768 + c * 64 + k] = v;
    pwork[side * 32768 + k * 512 + c] = v;
}

// ---------- K1: scoring, 2 points per thread, one side per blockIdx.y ----------
__global__ __launch_bounds__(256, 2) void k_score(const float* __restrict__ F,
                                                  const float* __restrict__ protoT,
                                                  float* __restrict__ md_fg,
                                                  float* __restrict__ md_bg,
                                                  float* __restrict__ n2out) {
    __shared__ float lds[2048];
    const int side = blockIdx.y;
    const int t = threadIdx.x;
    const int p0 = blockIdx.x * 512 + 2 * t;      // block covers 512 consecutive points
    const int n = p0 / HW;                        // 9216 % 512 == 0 -> no n crossing
    const int hw = p0 - n * HW;
    const float* Fp = F + (size_t)n * CHW + hw;
    const float* PT = protoT + side * 32768;

    float a0[64], a1[64];
#pragma unroll
    for (int k = 0; k < 64; ++k) { a0[k] = 0.f; a1[k] = 0.f; }
    float n20 = 0.f, n21 = 0.f;

    for (int cc = 0; cc < 16; ++cc) {
        __syncthreads();
#pragma unroll
        for (int i = 0; i < 8; ++i)
            lds[t + 256 * i] = PT[cc * 2048 + t + 256 * i];
        __syncthreads();
        for (int c = 0; c < 32; ++c) {
            float2 f = *(const float2*)(Fp + (size_t)(cc * 32 + c) * HW);
            if (side == 0) { n20 = fmaf(f.x, f.x, n20); n21 = fmaf(f.y, f.y, n21); }
#pragma unroll
            for (int k = 0; k < 64; ++k) {
                float pv = lds[c * 64 + k];
                a0[k] = fmaf(f.x, pv, a0[k]);
                a1[k] = fmaf(f.y, pv, a1[k]);
            }
        }
    }
    float m0 = a0[0], m1 = a1[0];
#pragma unroll
    for (int k = 1; k < 64; ++k) { m0 = fmaxf(m0, a0[k]); m1 = fmaxf(m1, a1[k]); }
    if (side == 0) {
        *(float2*)(md_fg + p0) = make_float2(m0, m1);
        *(float2*)(n2out + p0) = make_float2(n20, n21);
    } else {
        *(float2*)(md_bg + p0) = make_float2(m0, m1);
    }
}

// ---------- K1b: combine -> scores (in place), inv_norm, + radix hist pass 1 ----------
__global__ void k_combine(const float* __restrict__ M,
                          float* __restrict__ sfg, float* __restrict__ sbg,
                          float* __restrict__ n2inv, unsigned* __restrict__ hist) {
    int p = blockIdx.x * 256 + threadIdx.x;
    float inv = 1.f / fmaxf(sqrtf(n2inv[p]), 1e-8f);
    float m = fminf(fmaxf(M[p], 0.f), 1.f);
    float sf = (1.f - sfg[p] * inv) * m;
    float sb = (1.f - sbg[p] * inv) * (1.f - m);
    sfg[p] = sf; sbg[p] = sb; n2inv[p] = inv;
    atomicAdd(&hist[f2key(sf) >> 16], 1u);
    atomicAdd(&hist[65536 + (f2key(sb) >> 16)], 1u);
}

// ---------- radix pass 2 histogram ----------
__global__ void k_hist2(const float* __restrict__ sfg, const float* __restrict__ sbg,
                        const int* __restrict__ ctrl, unsigned* __restrict__ hist2) {
    int side = blockIdx.y;
    int p = blockIdx.x * 256 + threadIdx.x;
    float s = side ? sbg[p] : sfg[p];
    unsigned key = f2key(s);
    if ((int)(key >> 16) == ctrl[side * 8 + 0])
        atomicAdd(&hist2[side * 65536 + (key & 0xffffu)], 1u);
}

// ---------- scan: find threshold bucket (pass 0) / exact key (pass 1) ----------
__global__ __launch_bounds__(1024) void k_scan(const unsigned* __restrict__ hist,
                                               int* __restrict__ ctrl, int pass) {
    __shared__ unsigned sd[1024];
    int side = blockIdx.x;
    const unsigned* h = hist + side * 65536;
    int t = threadIdx.x;
    unsigned partial = 0;
    for (int j = 0; j < 64; ++j) partial += h[65535 - (t * 64 + j)];
    sd[t] = partial;
    __syncthreads();
    for (int off = 1; off < 1024; off <<= 1) {
        unsigned v = (t >= off) ? sd[t - off] : 0u;
        __syncthreads();
        sd[t] += v;
        __syncthreads();
    }
    unsigned incl = sd[t];
    unsigned excl = incl - partial;
    unsigned target = (pass == 0) ? 256u : (unsigned)ctrl[side * 8 + 1];
    if (excl < target && target <= incl) {
        unsigned cum = excl;
        for (int j = 0; j < 64; ++j) {
            int b = 65535 - (t * 64 + j);
            unsigned c = h[b];
            if (cum + c >= target) {
                if (pass == 0) {
                    ctrl[side * 8 + 0] = b;
                    ctrl[side * 8 + 1] = (int)(target - cum);
                } else {
                    unsigned vkey = ((unsigned)ctrl[side * 8 + 0] << 16) | (unsigned)b;
                    ctrl[side * 8 + 2] = (int)vkey;
                    int n_gt = (int)(256u - (unsigned)ctrl[side * 8 + 1] + cum);
                    ctrl[side * 8 + 3] = n_gt;
                    ctrl[side * 8 + 4] = 256 - n_gt;
                }
                break;
            }
            cum += c;
        }
    }
}

// ---------- collect indices ----------
__global__ void k_collect(const float* __restrict__ sfg, const float* __restrict__ sbg,
                          int* __restrict__ ctrl, int* __restrict__ idx, int* __restrict__ ties) {
    int side = blockIdx.y;
    int p = blockIdx.x * 256 + threadIdx.x;
    float s = side ? sbg[p] : sfg[p];
    unsigned key = f2key(s);
    unsigned vkey = (unsigned)ctrl[side * 8 + 2];
    if (key > vkey) {
        int pos = atomicAdd(&ctrl[side * 8 + 5], 1);
        idx[side * 256 + pos] = p;
    } else if (key == vkey) {
        int pos = atomicAdd(&ctrl[side * 8 + 6], 1);
        if (pos < 512) ties[side * 512 + pos] = p;
    }
}

// ---------- lightweight device-scope grid barrier ----------
__device__ __forceinline__ void gbar(unsigned* cnt, unsigned* gen, int nblocks) {
    __syncthreads();
    if (threadIdx.x == 0) {
        unsigned g = __hip_atomic_load(gen, __ATOMIC_RELAXED, __HIP_MEMORY_SCOPE_AGENT);
        unsigned arrived = __hip_atomic_fetch_add(cnt, 1u, __ATOMIC_ACQ_REL, __HIP_MEMORY_SCOPE_AGENT) + 1;
        if (arrived == (unsigned)nblocks) {
            __hip_atomic_store(cnt, 0u, __ATOMIC_RELAXED, __HIP_MEMORY_SCOPE_AGENT);
            __hip_atomic_fetch_add(gen, 1u, __ATOMIC_RELEASE, __HIP_MEMORY_SCOPE_AGENT);
        } else {
            while (__hip_atomic_load(gen, __ATOMIC_ACQUIRE, __HIP_MEMORY_SCOPE_AGENT) == g)
                __builtin_amdgcn_s_sleep(1);
        }
    }
    __syncthreads();
}

#define NB 256

// ---------- persistent tail: finalize + gather + 10x refine + loss + refined ----------
__global__ __launch_bounds__(256) void k_tail(const float* __restrict__ F,
                                              const float* __restrict__ invn,
                                              const float* __restrict__ fg,
                                              const float* __restrict__ bg,
                                              int* __restrict__ ctrl,
                                              int* __restrict__ idx,
                                              int* __restrict__ ties,
                                              float* __restrict__ feats,
                                              float* __restrict__ pwork,
                                              float* __restrict__ sums,   // reused as lpart
                                              float* __restrict__ cnts,
                                              unsigned* __restrict__ bar,
                                              float* __restrict__ out) {
    const int tid = threadIdx.x;
    const int bid = blockIdx.x;
    const int wv = tid >> 6;
    const int lane = tid & 63;
    unsigned* bcnt = bar;
    unsigned* bgen = bar + 16;

    // --- Phase A: tie finalize (smallest indices first, matches jax top_k) ---
    if (bid == 0 && tid < 2) {
        int side = tid;
        int n_gt = ctrl[side * 8 + 3];
        int need = ctrl[side * 8 + 4];
        int cnt = ctrl[side * 8 + 6];
        if (cnt > 512) cnt = 512;
        int* tb = ties + side * 512;
        for (int q = 0; q < need; ++q) {
            int mi = q;
            for (int j = q + 1; j < cnt; ++j) if (tb[j] < tb[mi]) mi = j;
            int tmp = tb[q]; tb[q] = tb[mi]; tb[mi] = tmp;
            idx[side * 256 + n_gt + q] = tb[q];
        }
    }
    gbar(bcnt, bgen, NB);

    const int pid = bid * 2 + wv;   // 0..511 when wv<2 (spread over all blocks)

    // --- Phase B: gather normalized selected features (wave per row) ---
    if (wv < 2) {
        int side = pid >> 8, j = pid & 255;
        int p = idx[side * 256 + j];
        float iv = invn[p];
        int n = p / HW, hw = p - n * HW;
        const float* Fp = F + (size_t)n * CHW + hw;
        float* o = feats + (size_t)pid * 512;
#pragma unroll
        for (int i = 0; i < 8; ++i) {
            int c = lane + i * 64;
            o[c] = Fp[(size_t)c * HW] * iv;
        }
    }
    gbar(bcnt, bgen, NB);

    // --- Phase C: 10 refinement iterations ---
    for (int it = 0; it < 10; ++it) {
        if (wv < 2) {   // assign: wave = (side, point); lane = cluster
            int side = pid >> 8;
            const float4* fr = (const float4*)(feats + (size_t)pid * 512);
            const float4* pw = (const float4*)(pwork + (size_t)side * 32768 + (size_t)lane * 512);
            float dot = 0.f;
#pragma unroll 4
            for (int c = 0; c < 128; ++c) {
                float4 a = fr[c], b = pw[c];
                dot = fmaf(a.x, b.x, dot); dot = fmaf(a.y, b.y, dot);
                dot = fmaf(a.z, b.z, dot); dot = fmaf(a.w, b.w, dot);
            }
            float bv = dot; int bi = lane;
#pragma unroll
            for (int mm = 32; mm >= 1; mm >>= 1) {
                float ov = __shfl_xor(bv, mm);
                int oi = __shfl_xor(bi, mm);
                if (ov > bv || (ov == bv && oi < bi)) { bv = ov; bi = oi; }
            }
            if (lane == 0) atomicAdd(&cnts[side * 64 + bi], 1.f);
            const float* frf = feats + (size_t)pid * 512;
            float* srow = sums + (size_t)side * 32768 + (size_t)bi * 512;
#pragma unroll
            for (int i = 0; i < 8; ++i) {
                int c = lane + i * 64;
                atomicAdd(&srow[c], frf[c]);
            }
        }
        gbar(bcnt, bgen, NB);
        if (wv == 2 && bid < 128) {   // update: (side, cluster) = bid; zero sums/cnts
            int side = bid >> 6, k = bid & 63;
            float step = (float)(0.1 / (1.0 + 0.5 * (double)it));
            float cnt = cnts[side * 64 + k];
            float* srow = sums + (size_t)side * 32768 + (size_t)k * 512;
            float* prow = pwork + (size_t)side * 32768 + (size_t)k * 512;
            float bl[8]; float n2 = 0.f;
#pragma unroll
            for (int i = 0; i < 8; ++i) {
                int c = lane + i * 64;
                float mean = srow[c] / fmaxf(cnt, 1.f);
                float v = (1.f - step) * prow[c] + step * mean;
                bl[i] = v; n2 = fmaf(v, v, n2);
                srow[c] = 0.f;
            }
#pragma unroll
            for (int mm = 32; mm >= 1; mm >>= 1) n2 += __shfl_xor(n2, mm);
            float inv = 1.f / fmaxf(sqrtf(n2), 1e-8f);
            if (cnt > 0.f) {
#pragma unroll
                for (int i = 0; i < 8; ++i) prow[lane + i * 64] = bl[i] * inv;
            }
            if (lane == 0) cnts[side * 64 + k] = 0.f;
        }
        gbar(bcnt, bgen, NB);
    }

    // --- Phase D: loss partials (sums reused as lpart) ---
    float* lpart = sums;
    if (wv < 2) {
        int half = pid >> 8, j = pid & 255;
        const float4* fr = (const float4*)(feats + (size_t)pid * 512);
        const float4* pf = (const float4*)(pwork + (size_t)lane * 512);
        const float4* pb = (const float4*)(pwork + 32768 + (size_t)lane * 512);
        if (half == 0) {
            float d1 = 0.f, d2 = 0.f;
            for (int c = 0; c < 128; ++c) {
                float4 a = fr[c], x = pf[c], y = pb[c];
                d1 = fmaf(a.x, x.x, d1); d1 = fmaf(a.y, x.y, d1);
                d1 = fmaf(a.z, x.z, d1); d1 = fmaf(a.w, x.w, d1);
                d2 = fmaf(a.x, y.x, d2); d2 = fmaf(a.y, y.y, d2);
                d2 = fmaf(a.z, y.z, d2); d2 = fmaf(a.w, y.w, d2);
            }
            float smax = d1;
            for (int mm = 32; mm >= 1; mm >>= 1) smax = fmaxf(smax, __shfl_xor(smax, mm));
            float a = d1 / 0.07f, b = d2 / 0.07f;
            float m1 = a;
            for (int mm = 32; mm >= 1; mm >>= 1) m1 = fmaxf(m1, __shfl_xor(m1, mm));
            float mbv = b;
            for (int mm = 32; mm >= 1; mm >>= 1) mbv = fmaxf(mbv, __shfl_xor(mbv, mm));
            float md = fmaxf(m1, mbv);
            float sn = expf(a - m1);
            for (int mm = 32; mm >= 1; mm >>= 1) sn += __shfl_xor(sn, mm);
            float sdn = expf(a - md) + expf(b - md);
            for (int mm = 32; mm >= 1; mm >>= 1) sdn += __shfl_xor(sdn, mm);
            float num = m1 + logf(sn);
            float den = md + logf(sdn);
            if (lane == 0) { lpart[j] = smax; lpart[512 + j] = num - den; }
        } else {
            float d1 = 0.f;
            for (int c = 0; c < 128; ++c) {
                float4 a = fr[c], x = pf[c];
                d1 = fmaf(a.x, x.x, d1); d1 = fmaf(a.y, x.y, d1);
                d1 = fmaf(a.z, x.z, d1); d1 = fmaf(a.w, x.w, d1);
            }
            float smax = d1;
            for (int mm = 32; mm >= 1; mm >>= 1) smax = fmaxf(smax, __shfl_xor(smax, mm));
            if (lane == 0) lpart[256 + j] = smax;
        }
    }
    gbar(bcnt, bgen, NB);

    // --- Phase E: final loss (block 0) + refined protos (blocks 128..255, wave 3) ---
    if (bid == 0) {
        __shared__ float red[3][4];
        float sp = lpart[tid], sn = lpart[256 + tid], nm = lpart[512 + tid];
        for (int mm = 32; mm >= 1; mm >>= 1) {
            sp += __shfl_xor(sp, mm); sn += __shfl_xor(sn, mm); nm += __shfl_xor(nm, mm);
        }
        if ((tid & 63) == 0) { red[0][wv] = sp; red[1][wv] = sn; red[2][wv] = nm; }
        __syncthreads();
        if (tid == 0) {
            float SP = 0, SN = 0, NM = 0;
            for (int i = 0; i < 4; ++i) { SP += red[0][i]; SN += red[1][i]; NM += red[2][i]; }
            SP /= 256.f; SN /= 256.f; NM /= 256.f;
            out[0] = fmaxf(0.f, 0.2f + SN - SP) + 0.25f * (-NM);
        }
    }
    if (wv == 3 && bid >= 128) {
        int w2 = bid - 128;     // 0..127
        int side = w2 >> 6, k = w2 & 63;
        const float* proto = (side ? bg : fg) + (size_t)k * 512;
        const float* prow = pwork + (size_t)side * 32768 + (size_t)k * 512;
        float bl[8]; float n2 = 0.f;
#pragma unroll
        for (int i = 0; i < 8; ++i) {
            int c = lane + i * 64;
            float v = 0.7f * proto[c] + 0.3f * prow[c];
            bl[i] = v; n2 = fmaf(v, v, n2);
        }
#pragma unroll
        for (int mm = 32; mm >= 1; mm >>= 1) n2 += __shfl_xor(n2, mm);
        float inv = 1.f / fmaxf(sqrtf(n2), 1e-8f);
        float* o = out + 1 + (size_t)side * 32768 + (size_t)k * 512;
#pragma unroll
        for (int i = 0; i < 8; ++i) o[lane + i * 64] = bl[i] * inv;
    }
}

extern "C" void kernel_launch(void* const* d_in, const int* in_sizes, int n_in,
                              void* d_out, int out_size, void* d_ws, size_t ws_size,
                              hipStream_t stream) {
    const float* fg = (const float*)d_in[0];
    const float* bg = (const float*)d_in[1];
    const float* F  = (const float*)d_in[2];
    const float* M  = (const float*)d_in[3];
    float* out = (float*)d_out;
    char* ws = (char*)d_ws;

    size_t o = 0;
    auto alloc = [&](size_t bytes) { size_t r = o; o += (bytes + 1023) & ~(size_t)1023; return r; };
    // zeroed region (one memset covers it)
    size_t off_hist1 = alloc(2 * 65536 * 4);
    size_t off_hist2 = alloc(2 * 65536 * 4);
    size_t off_ctrl  = alloc(64);
    size_t off_cnts  = alloc(2 * 64 * 4);
    size_t off_sums  = alloc(2 * 64 * 512 * 4);
    size_t off_bar   = alloc(128);
    size_t zbytes = o;
    size_t off_sfg   = alloc(P_TOTAL * 4);
    size_t off_sbg   = alloc(P_TOTAL * 4);
    size_t off_inv   = alloc(P_TOTAL * 4);
    size_t off_pT    = alloc(2 * 512 * 64 * 4);
    size_t off_idx   = alloc(2 * 256 * 4);
    size_t off_ties  = alloc(2 * 512 * 4);
    size_t off_feats = alloc(2 * 256 * 512 * 4);
    size_t off_pwork = alloc(2 * 64 * 512 * 4);

    unsigned* hist1 = (unsigned*)(ws + off_hist1);
    unsigned* hist2 = (unsigned*)(ws + off_hist2);
    int* ctrl   = (int*)(ws + off_ctrl);
    float* cnts = (float*)(ws + off_cnts);
    float* sums = (float*)(ws + off_sums);
    unsigned* bar = (unsigned*)(ws + off_bar);
    float* sfg  = (float*)(ws + off_sfg);
    float* sbg  = (float*)(ws + off_sbg);
    float* invn = (float*)(ws + off_inv);
    float* pT   = (float*)(ws + off_pT);
    int* idx    = (int*)(ws + off_idx);
    int* ties   = (int*)(ws + off_ties);
    float* feats = (float*)(ws + off_feats);
    float* pwork = (float*)(ws + off_pwork);

    hipMemsetAsync(ws, 0, zbytes, stream);
    k_init<<<256, 256, 0, stream>>>(fg, bg, pT, pwork);
    k_score<<<dim3(288, 2), 256, 0, stream>>>(F, pT, sfg, sbg, invn);
    k_combine<<<576, 256, 0, stream>>>(M, sfg, sbg, invn, hist1);
    k_scan<<<2, 1024, 0, stream>>>(hist1, ctrl, 0);
    k_hist2<<<dim3(576, 2), 256, 0, stream>>>(sfg, sbg, ctrl, hist2);
    k_scan<<<2, 1024, 0, stream>>>(hist2, ctrl, 1);
    k_collect<<<dim3(576, 2), 256, 0, stream>>>(sfg, sbg, ctrl, idx, ties);

    void* args[] = {(void*)&F, (void*)&invn, (void*)&fg, (void*)&bg,
                    (void*)&ctrl, (void*)&idx, (void*)&ties, (void*)&feats,
                    (void*)&pwork, (void*)&sums, (void*)&cnts, (void*)&bar, (void*)&out};
    hipLaunchCooperativeKernel((const void*)k_tail, dim3(NB), dim3(256),
                               args, 0, stream);
}

// Round 4
// 1303.274 us; speedup vs baseline: 1.3328x; 1.3328x over previous
//
#include <hip/hip_runtime.h>
#include <math.h>

#define P_TOTAL 147456
#define HW 9216
#define CHW (512*9216)

__device__ __forceinline__ unsigned f2key(float f) {
    unsigned u = __float_as_uint(f);
    return (u & 0x80000000u) ? ~u : (u | 0x80000000u);
}

// ---------- K0: pack protos to [c][side*64+k] ----------
__global__ void k_init(const float* __restrict__ fg, const float* __restrict__ bg,
                       float* __restrict__ pT) {
    int i = blockIdx.x * 256 + threadIdx.x;   // 0..65535
    int side = i >> 15, r = i & 32767, k = r >> 9, c = r & 511;
    pT[c * 128 + side * 64 + k] = (side ? bg : fg)[k * 512 + c];
}

// ---------- K1: register-tiled scoring GEMM: 256 pts x 128 protos per block ----------
// thread: 4 points x 32 protos. Fused: norm2, combine with M, radix hist pass 1.
__global__ __launch_bounds__(256, 2) void k_score(const float* __restrict__ F,
                                                  const float* __restrict__ pT,
                                                  const float* __restrict__ M,
                                                  float* __restrict__ sfg,
                                                  float* __restrict__ sbg,
                                                  float* __restrict__ invn,
                                                  unsigned* __restrict__ hist) {
    __shared__ float As[16 * 256];
    __shared__ float Bs[16 * 128];
    __shared__ float sql[4 * 64 * 4];
    __shared__ float mxs[256 * 4];
    const int t = threadIdx.x;
    const int p0 = blockIdx.x * 256;
    const int n = p0 / HW;
    const int hw0 = p0 - n * HW;
    const float* Fb = F + (size_t)n * CHW + hw0;
    const int pm = t & 63;     // point group (4 consecutive points)
    const int pn = t >> 6;     // proto range pn*32..+31 (0,1=fg; 2,3=bg)
    const int kk4 = t >> 6;    // staging role
    const int pg = t & 63;

    float acc[4][32];
#pragma unroll
    for (int i = 0; i < 4; ++i)
#pragma unroll
        for (int j = 0; j < 32; ++j) acc[i][j] = 0.f;
    float4 sq = make_float4(0.f, 0.f, 0.f, 0.f);

    for (int ch = 0; ch < 32; ++ch) {
        const int c0 = ch * 16;
        __syncthreads();
        // stage A (16 c x 256 pts) + accumulate squares
#pragma unroll
        for (int r = 0; r < 4; ++r) {
            int kk = r * 4 + kk4;
            float4 v = *(const float4*)(Fb + (size_t)(c0 + kk) * HW + pg * 4);
            *(float4*)(As + kk * 256 + pg * 4) = v;
            sq.x = fmaf(v.x, v.x, sq.x); sq.y = fmaf(v.y, v.y, sq.y);
            sq.z = fmaf(v.z, v.z, sq.z); sq.w = fmaf(v.w, v.w, sq.w);
        }
        // stage B (16 c x 128 protos)
        {
            int e0 = t * 8;
            const float* src = pT + (size_t)c0 * 128 + e0;
            float4 b0 = *(const float4*)(src);
            float4 b1 = *(const float4*)(src + 4);
            *(float4*)(Bs + e0) = b0;
            *(float4*)(Bs + e0 + 4) = b1;
        }
        __syncthreads();
#pragma unroll 2
        for (int kk = 0; kk < 16; ++kk) {
            float4 av = *(const float4*)(As + kk * 256 + pm * 4);
            const float* Bk = Bs + kk * 128 + pn * 32;
#pragma unroll
            for (int j = 0; j < 32; ++j) {
                float b = Bk[j];
                acc[0][j] = fmaf(av.x, b, acc[0][j]);
                acc[1][j] = fmaf(av.y, b, acc[1][j]);
                acc[2][j] = fmaf(av.z, b, acc[2][j]);
                acc[3][j] = fmaf(av.w, b, acc[3][j]);
            }
        }
    }
    // deterministic n2 partials
    *(float4*)(sql + (kk4 * 64 + pg) * 4) = sq;
#pragma unroll
    for (int i = 0; i < 4; ++i) {
        float m2 = acc[i][0];
#pragma unroll
        for (int j = 1; j < 32; ++j) m2 = fmaxf(m2, acc[i][j]);
        mxs[(pm * 4 + i) * 4 + pn] = m2;
    }
    __syncthreads();
    if (t < 256) {
        int p = t;
        float n2 = sql[(0 * 64 + (p >> 2)) * 4 + (p & 3)]
                 + sql[(1 * 64 + (p >> 2)) * 4 + (p & 3)]
                 + sql[(2 * 64 + (p >> 2)) * 4 + (p & 3)]
                 + sql[(3 * 64 + (p >> 2)) * 4 + (p & 3)];
        float inv = 1.f / fmaxf(sqrtf(n2), 1e-8f);
        float mf = fmaxf(mxs[p * 4 + 0], mxs[p * 4 + 1]);
        float mb = fmaxf(mxs[p * 4 + 2], mxs[p * 4 + 3]);
        float m = fminf(fmaxf(M[p0 + p], 0.f), 1.f);
        float sf = (1.f - mf * inv) * m;
        float sb = (1.f - mb * inv) * (1.f - m);
        sfg[p0 + p] = sf; sbg[p0 + p] = sb; invn[p0 + p] = inv;
        atomicAdd(&hist[f2key(sf) >> 16], 1u);
        atomicAdd(&hist[65536 + (f2key(sb) >> 16)], 1u);
    }
}

// ---------- scan: find threshold bucket (pass 0) / exact key (pass 1) ----------
__global__ __launch_bounds__(1024) void k_scan(const unsigned* __restrict__ hist,
                                               int* __restrict__ ctrl, int pass) {
    __shared__ unsigned sd[1024];
    int side = blockIdx.x;
    const unsigned* h = hist + side * 65536;
    int t = threadIdx.x;
    unsigned partial = 0;
    for (int j = 0; j < 64; ++j) partial += h[65535 - (t * 64 + j)];
    sd[t] = partial;
    __syncthreads();
    for (int off = 1; off < 1024; off <<= 1) {
        unsigned v = (t >= off) ? sd[t - off] : 0u;
        __syncthreads();
        sd[t] += v;
        __syncthreads();
    }
    unsigned incl = sd[t];
    unsigned excl = incl - partial;
    unsigned target = (pass == 0) ? 256u : (unsigned)ctrl[side * 8 + 1];
    if (excl < target && target <= incl) {
        unsigned cum = excl;
        for (int j = 0; j < 64; ++j) {
            int b = 65535 - (t * 64 + j);
            unsigned c = h[b];
            if (cum + c >= target) {
                if (pass == 0) {
                    ctrl[side * 8 + 0] = b;
                    ctrl[side * 8 + 1] = (int)(target - cum);
                } else {
                    unsigned vkey = ((unsigned)ctrl[side * 8 + 0] << 16) | (unsigned)b;
                    ctrl[side * 8 + 2] = (int)vkey;
                    int n_gt = (int)(256u - (unsigned)ctrl[side * 8 + 1] + cum);
                    ctrl[side * 8 + 3] = n_gt;
                    ctrl[side * 8 + 4] = 256 - n_gt;
                }
                break;
            }
            cum += c;
        }
    }
}

__global__ void k_hist2(const float* __restrict__ sfg, const float* __restrict__ sbg,
                        const int* __restrict__ ctrl, unsigned* __restrict__ hist2) {
    int side = blockIdx.y;
    int p = blockIdx.x * 256 + threadIdx.x;
    float s = side ? sbg[p] : sfg[p];
    unsigned key = f2key(s);
    if ((int)(key >> 16) == ctrl[side * 8 + 0])
        atomicAdd(&hist2[side * 65536 + (key & 0xffffu)], 1u);
}

// ---------- collect + inline gather of normalized rows ----------
__global__ void k_collect(const float* __restrict__ sfg, const float* __restrict__ sbg,
                          const float* __restrict__ invn, const float* __restrict__ F,
                          int* __restrict__ ctrl, int* __restrict__ ties,
                          float* __restrict__ feats, float* __restrict__ tiefeats) {
    int side = blockIdx.y;
    int p = blockIdx.x * 256 + threadIdx.x;
    float s = side ? sbg[p] : sfg[p];
    unsigned key = f2key(s);
    unsigned vkey = (unsigned)ctrl[side * 8 + 2];
    float* base = nullptr;
    if (key > vkey) {
        int pos = atomicAdd(&ctrl[side * 8 + 5], 1);
        base = feats + (size_t)(side * 256 + pos) * 512;
    } else if (key == vkey) {
        int pos = atomicAdd(&ctrl[side * 8 + 6], 1);
        if (pos < 512) ties[side * 512 + pos] = p;
        if (pos < 256) base = tiefeats + (size_t)(side * 256 + pos) * 512;
    }
    if (base) {
        int n = p / HW, hw = p - n * HW;
        float iv = invn[p];
        const float* Fp = F + (size_t)n * CHW + hw;
        for (int c = 0; c < 512; ++c) base[c] = Fp[(size_t)c * HW] * iv;
    }
}

// ---------- prep: redundant tie-resolve per block; G tiles, D0 tiles, feats finalize ----------
__global__ __launch_bounds__(256) void k_prep(const float* __restrict__ fg,
                                              const float* __restrict__ bg,
                                              const int* __restrict__ ctrl,
                                              const int* __restrict__ ties,
                                              const float* __restrict__ tiefeats,
                                              float* __restrict__ feats,
                                              float* __restrict__ G,
                                              float* __restrict__ D0,
                                              float* __restrict__ beta) {
    const int side = blockIdx.x & 1;
    const int role = blockIdx.x >> 1;   // 0..15 G tiles; 16..19 D0; 20 finalize
    const int tid = threadIdx.x;
    __shared__ int skey[512];
    __shared__ int sslot[512];
    __shared__ const float* rp[256];
    __shared__ float At[64 * 33];
    __shared__ float Bt[64 * 33];

    int n_gt = ctrl[side * 8 + 3];
    int need = ctrl[side * 8 + 4];
    int cnt = ctrl[side * 8 + 6]; if (cnt > 512) cnt = 512;
    for (int i = tid; i < 512; i += 256) {
        if (i < cnt) { skey[i] = ties[side * 512 + i]; sslot[i] = i; }
        else { skey[i] = 0x7fffffff; sslot[i] = -1; }
    }
    __syncthreads();
    for (int ksz = 2; ksz <= 512; ksz <<= 1) {
        for (int jsz = ksz >> 1; jsz > 0; jsz >>= 1) {
            for (int i = tid; i < 512; i += 256) {
                int l = i ^ jsz;
                if (l > i) {
                    bool up = ((i & ksz) == 0);
                    int a = skey[i], b = skey[l];
                    if ((a > b) == up) {
                        skey[i] = b; skey[l] = a;
                        int t2 = sslot[i]; sslot[i] = sslot[l]; sslot[l] = t2;
                    }
                }
            }
            __syncthreads();
        }
    }
    for (int j = tid; j < 256; j += 256) {
        rp[j] = (j < n_gt) ? feats + (size_t)(side * 256 + j) * 512
                           : tiefeats + (size_t)(side * 256 + sslot[j - n_gt]) * 512;
    }
    __syncthreads();

    if (role == 20) {
        for (int q = 0; q < need; ++q) {
            const float* src = tiefeats + (size_t)(side * 256 + sslot[q]) * 512;
            float* dst = feats + (size_t)(side * 256 + n_gt + q) * 512;
            for (int e = tid; e < 512; e += 256) dst[e] = src[e];
        }
        if (tid < 64) beta[side * 64 + tid] = 1.f;
        return;
    }

    const int i2 = tid >> 2;
    const int cp = (tid & 3) * 8;
    const int ti = tid >> 4, tj = tid & 15;
    float accg[4][4];
#pragma unroll
    for (int a = 0; a < 4; ++a)
#pragma unroll
        for (int b = 0; b < 4; ++b) accg[a][b] = 0.f;

    if (role < 16) {   // G tile
        int r = role >> 2, ct = role & 3;
        for (int ch = 0; ch < 16; ++ch) {
            int c0 = ch * 32;
            __syncthreads();
            {
                const float* ra = rp[r * 64 + i2];
                const float* rb = rp[ct * 64 + i2];
                float4 u0 = *(const float4*)(ra + c0 + cp);
                float4 u1 = *(const float4*)(ra + c0 + cp + 4);
                float4 v0 = *(const float4*)(rb + c0 + cp);
                float4 v1 = *(const float4*)(rb + c0 + cp + 4);
                float* ap = At + i2 * 33 + cp;
                float* bp = Bt + i2 * 33 + cp;
                ap[0]=u0.x; ap[1]=u0.y; ap[2]=u0.z; ap[3]=u0.w;
                ap[4]=u1.x; ap[5]=u1.y; ap[6]=u1.z; ap[7]=u1.w;
                bp[0]=v0.x; bp[1]=v0.y; bp[2]=v0.z; bp[3]=v0.w;
                bp[4]=v1.x; bp[5]=v1.y; bp[6]=v1.z; bp[7]=v1.w;
            }
            __syncthreads();
            for (int cc = 0; cc < 32; ++cc) {
                float av[4], bv[4];
#pragma unroll
                for (int a = 0; a < 4; ++a) av[a] = At[(ti * 4 + a) * 33 + cc];
#pragma unroll
                for (int b = 0; b < 4; ++b) bv[b] = Bt[(tj * 4 + b) * 33 + cc];
#pragma unroll
                for (int a = 0; a < 4; ++a)
#pragma unroll
                    for (int b = 0; b < 4; ++b) accg[a][b] = fmaf(av[a], bv[b], accg[a][b]);
            }
        }
#pragma unroll
        for (int a = 0; a < 4; ++a)
#pragma unroll
            for (int b = 0; b < 4; ++b)
                G[side * 65536 + (r * 64 + ti * 4 + a) * 256 + ct * 64 + tj * 4 + b] = accg[a][b];
    } else {          // D0 tile: 64 points x 64 protos
        int r4 = role - 16;
        const float* proto = side ? bg : fg;
        for (int ch = 0; ch < 16; ++ch) {
            int c0 = ch * 32;
            __syncthreads();
            {
                const float* ra = rp[r4 * 64 + i2];
                float4 u0 = *(const float4*)(ra + c0 + cp);
                float4 u1 = *(const float4*)(ra + c0 + cp + 4);
                const float* rb = proto + (size_t)i2 * 512;
                float4 v0 = *(const float4*)(rb + c0 + cp);
                float4 v1 = *(const float4*)(rb + c0 + cp + 4);
                float* ap = At + i2 * 33 + cp;
                float* bp = Bt + i2 * 33 + cp;
                ap[0]=u0.x; ap[1]=u0.y; ap[2]=u0.z; ap[3]=u0.w;
                ap[4]=u1.x; ap[5]=u1.y; ap[6]=u1.z; ap[7]=u1.w;
                bp[0]=v0.x; bp[1]=v0.y; bp[2]=v0.z; bp[3]=v0.w;
                bp[4]=v1.x; bp[5]=v1.y; bp[6]=v1.z; bp[7]=v1.w;
            }
            __syncthreads();
            for (int cc = 0; cc < 32; ++cc) {
                float av[4], bv[4];
#pragma unroll
                for (int a = 0; a < 4; ++a) av[a] = At[(ti * 4 + a) * 33 + cc];
#pragma unroll
                for (int b = 0; b < 4; ++b) bv[b] = Bt[(tj * 4 + b) * 33 + cc];
#pragma unroll
                for (int a = 0; a < 4; ++a)
#pragma unroll
                    for (int b = 0; b < 4; ++b) accg[a][b] = fmaf(av[a], bv[b], accg[a][b]);
            }
        }
#pragma unroll
        for (int a = 0; a < 4; ++a)
#pragma unroll
            for (int b = 0; b < 4; ++b)
                D0[side * 16384 + (r4 * 64 + ti * 4 + a) * 64 + tj * 4 + b] = accg[a][b];
    }
}

// ---------- iterate: one block per side, 10 k-means steps in dots/coefficient space ----------
__global__ __launch_bounds__(1024, 1) void k_iter(const float* __restrict__ G,
                                                  const float* __restrict__ D0,
                                                  float* __restrict__ gamma,
                                                  float* __restrict__ beta,
                                                  float* __restrict__ dotsF) {
    const int side = blockIdx.x;
    __shared__ float dots[256 * 65];
    __shared__ float S[256 * 65];
    __shared__ int assign_[256];
    __shared__ int ord[256];
    __shared__ int cnt[64];
    __shared__ int segst[64];
    __shared__ int cur[64];
    __shared__ float sdot[64], SSs[64], a_om[64], a_t[64];
    const int tid = threadIdx.x;
    const int p = tid >> 2, q = tid & 3;
    const float* Gs = G + side * 65536;
    float* gam = gamma + side * 16384;

    for (int e = tid; e < 16384; e += 1024) {
        int pp = e >> 6, kk = e & 63;
        dots[pp * 65 + kk] = D0[side * 16384 + e];
    }
    __syncthreads();

    for (int it = 0; it < 10; ++it) {
        float s = 0.1f / (1.f + 0.5f * (float)it);
        // argmax over dots row (first-index tie rule)
        float bv = -1e30f; int bk = 64;
#pragma unroll
        for (int j = 0; j < 16; ++j) {
            int k = q * 16 + j;
            float v = dots[p * 65 + k];
            if (v > bv) { bv = v; bk = k; }
        }
        {
            float ov = __shfl_xor(bv, 1); int ok = __shfl_xor(bk, 1);
            if (ov > bv || (ov == bv && ok < bk)) { bv = ov; bk = ok; }
            ov = __shfl_xor(bv, 2); ok = __shfl_xor(bk, 2);
            if (ov > bv || (ov == bv && ok < bk)) { bv = ov; bk = ok; }
        }
        if (q == 0) assign_[p] = bk;
        if (tid < 64) { cnt[tid] = 0; sdot[tid] = 0.f; SSs[tid] = 0.f; }
        __syncthreads();
        if (q == 0) atomicAdd(&cnt[bk], 1);
        __syncthreads();
        if (tid == 0) {
            int acc2 = 0;
            for (int k = 0; k < 64; ++k) { segst[k] = acc2; cur[k] = acc2; acc2 += cnt[k]; }
        }
        __syncthreads();
        if (q == 0) { int pos = atomicAdd(&cur[bk], 1); ord[pos] = p; }
        __syncthreads();
        // S[i][k] = sum over j in cluster k of G[i][j]
#pragma unroll 4
        for (int t16 = 0; t16 < 16; ++t16) {
            int k = q + 4 * t16;
            float a2 = 0.f;
            int b0 = segst[k], e0 = b0 + cnt[k];
            for (int j = b0; j < e0; ++j) a2 += Gs[p * 256 + ord[j]];
            S[p * 65 + k] = a2;
        }
        __syncthreads();
        if (q == 0) {
            int a = assign_[p];
            atomicAdd(&SSs[a], S[p * 65 + a]);
            atomicAdd(&sdot[a], dots[p * 65 + a]);
        }
        __syncthreads();
        if (tid < 64) {
            int c = cnt[tid];
            if (c > 0) {
                float om = 1.f - s, tt = s / (float)c;
                float nr2 = om * om + 2.f * om * tt * sdot[tid] + tt * tt * SSs[tid];
                float al = 1.f / fmaxf(sqrtf(nr2), 1e-8f);
                a_om[tid] = al * om; a_t[tid] = al * tt;
                beta[side * 64 + tid] *= al * om;
            } else { a_om[tid] = 1.f; a_t[tid] = 0.f; }
        }
        __syncthreads();
#pragma unroll 4
        for (int t16 = 0; t16 < 16; ++t16) {
            int k = q + 4 * t16;
            dots[p * 65 + k] = a_om[k] * dots[p * 65 + k] + a_t[k] * S[p * 65 + k];
        }
#pragma unroll 4
        for (int r = 0; r < 16; ++r) {
            int e = tid + 1024 * r;
            int k = e >> 8, i = e & 255;
            if (cnt[k] > 0) {
                float g = gam[e];
                gam[e] = a_om[k] * g + (assign_[i] == k ? a_t[k] : 0.f);
            }
        }
        __syncthreads();
    }
    for (int e = tid; e < 16384; e += 1024) {
        int pp = e >> 6, kk = e & 63;
        dotsF[side * 16384 + e] = dots[pp * 65 + kk];
    }
}

// ---------- reconstruct p_final from coefficients; write refined outputs ----------
__global__ __launch_bounds__(256) void k_recon(const float* __restrict__ fg,
                                               const float* __restrict__ bg,
                                               const float* __restrict__ feats,
                                               const float* __restrict__ gamma,
                                               const float* __restrict__ beta,
                                               float* __restrict__ pfin,
                                               float* __restrict__ out) {
    const int side = blockIdx.x >> 6, k = blockIdx.x & 63;
    const int tid = threadIdx.x;
    __shared__ float gml[256];
    __shared__ float red[4];
    gml[tid] = gamma[side * 16384 + k * 256 + tid];
    __syncthreads();
    const float* p0 = (side ? bg : fg) + (size_t)k * 512;
    float b = beta[side * 64 + k];
    float v0 = b * p0[tid];
    float v1 = b * p0[tid + 256];
    const float* fb = feats + (size_t)side * 256 * 512;
    for (int i = 0; i < 256; ++i) {
        float g = gml[i];
        v0 = fmaf(g, fb[(size_t)i * 512 + tid], v0);
        v1 = fmaf(g, fb[(size_t)i * 512 + tid + 256], v1);
    }
    pfin[(size_t)(side * 64 + k) * 512 + tid] = v0;
    pfin[(size_t)(side * 64 + k) * 512 + tid + 256] = v1;
    float r0 = 0.7f * p0[tid] + 0.3f * v0;
    float r1 = 0.7f * p0[tid + 256] + 0.3f * v1;
    float nn = r0 * r0 + r1 * r1;
    for (int mm = 32; mm >= 1; mm >>= 1) nn += __shfl_xor(nn, mm);
    if ((tid & 63) == 0) red[tid >> 6] = nn;
    __syncthreads();
    float tot = red[0] + red[1] + red[2] + red[3];
    float inv = 1.f / fmaxf(sqrtf(tot), 1e-8f);
    out[1 + side * 32768 + k * 512 + tid] = r0 * inv;
    out[1 + side * 32768 + k * 512 + tid + 256] = r1 * inv;
}

// ---------- loss: cross sims + triplet + InfoNCE; last block writes out[0] ----------
__global__ __launch_bounds__(256, 1) void k_loss(const float* __restrict__ feats,
                                                 const float* __restrict__ pfin,
                                                 const float* __restrict__ dotsF,
                                                 float* __restrict__ lacc,
                                                 unsigned* __restrict__ lcnt,
                                                 float* __restrict__ out) {
    __shared__ float P[64 * 513];
    __shared__ float fr[4 * 512];
    const int bid = blockIdx.x, tid = threadIdx.x;
    const int w = tid >> 6, lane = tid & 63;
    const int posrole = (bid < 64) ? 1 : 0;
    const float* Pg = pfin + (posrole ? 32768 : 0);          // pos->p_bg, neg->p_fg
    const float* fsrc = feats + (posrole ? 0 : 131072);
    for (int e = tid; e < 32768; e += 256) {
        int k = e >> 9, c = e & 511;
        P[k * 513 + c] = Pg[e];
    }
    int pbase = (bid & 63) * 4;
    for (int e = tid; e < 2048; e += 256) fr[e] = fsrc[(size_t)pbase * 512 + e];
    __syncthreads();
    int p = pbase + w;
    float d = 0.f;
    for (int c = 0; c < 512; ++c) d = fmaf(fr[w * 512 + c], P[lane * 513 + c], d);
    if (posrole) {
        float ps = dotsF[p * 64 + lane];
        float smax = ps;
        for (int mm = 32; mm >= 1; mm >>= 1) smax = fmaxf(smax, __shfl_xor(smax, mm));
        float a = ps / 0.07f, bq = d / 0.07f;
        float m1 = a;
        for (int mm = 32; mm >= 1; mm >>= 1) m1 = fmaxf(m1, __shfl_xor(m1, mm));
        float bmax = bq;
        for (int mm = 32; mm >= 1; mm >>= 1) bmax = fmaxf(bmax, __shfl_xor(bmax, mm));
        float mall = fmaxf(m1, bmax);
        float se1 = expf(a - m1);
        for (int mm = 32; mm >= 1; mm >>= 1) se1 += __shfl_xor(se1, mm);
        float se2 = expf(a - mall) + expf(bq - mall);
        for (int mm = 32; mm >= 1; mm >>= 1) se2 += __shfl_xor(se2, mm);
        float num = m1 + logf(se1);
        float den = mall + logf(se2);
        if (lane == 0) { atomicAdd(&lacc[0], smax); atomicAdd(&lacc[2], num - den); }
    } else {
        float smax = d;
        for (int mm = 32; mm >= 1; mm >>= 1) smax = fmaxf(smax, __shfl_xor(smax, mm));
        if (lane == 0) atomicAdd(&lacc[1], smax);
    }
    __threadfence();
    if (lane == 0) {
        unsigned done = __hip_atomic_fetch_add(lcnt, 1u, __ATOMIC_ACQ_REL, __HIP_MEMORY_SCOPE_AGENT) + 1;
        if (done == 512u) {
            float SP = __hip_atomic_load(&lacc[0], __ATOMIC_RELAXED, __HIP_MEMORY_SCOPE_AGENT);
            float SN = __hip_atomic_load(&lacc[1], __ATOMIC_RELAXED, __HIP_MEMORY_SCOPE_AGENT);
            float NM = __hip_atomic_load(&lacc[2], __ATOMIC_RELAXED, __HIP_MEMORY_SCOPE_AGENT);
            out[0] = fmaxf(0.f, 0.2f + SN / 256.f - SP / 256.f) - 0.25f * (NM / 256.f);
        }
    }
}

extern "C" void kernel_launch(void* const* d_in, const int* in_sizes, int n_in,
                              void* d_out, int out_size, void* d_ws, size_t ws_size,
                              hipStream_t stream) {
    const float* fg = (const float*)d_in[0];
    const float* bg = (const float*)d_in[1];
    const float* F  = (const float*)d_in[2];
    const float* M  = (const float*)d_in[3];
    float* out = (float*)d_out;
    char* ws = (char*)d_ws;

    size_t o = 0;
    auto alloc = [&](size_t bytes) { size_t r = o; o += (bytes + 1023) & ~(size_t)1023; return r; };
    // zeroed region
    size_t off_hist1 = alloc(2 * 65536 * 4);
    size_t off_hist2 = alloc(2 * 65536 * 4);
    size_t off_ctrl  = alloc(64);
    size_t off_gamma = alloc(2 * 64 * 256 * 4);
    size_t off_lacc  = alloc(64);
    size_t zbytes = o;
    // rest
    size_t off_sfg   = alloc(P_TOTAL * 4);
    size_t off_sbg   = alloc(P_TOTAL * 4);
    size_t off_inv   = alloc(P_TOTAL * 4);
    size_t off_pT    = alloc(512 * 128 * 4);
    size_t off_ties  = alloc(2 * 512 * 4);
    size_t off_feats = alloc(2 * 256 * 512 * 4);
    size_t off_tief  = alloc(2 * 256 * 512 * 4);
    size_t off_G     = alloc(2 * 256 * 256 * 4);
    size_t off_D0    = alloc(2 * 256 * 64 * 4);
    size_t off_beta  = alloc(2 * 64 * 4);
    size_t off_dotsF = alloc(2 * 256 * 64 * 4);
    size_t off_pfin  = alloc(2 * 64 * 512 * 4);

    unsigned* hist1 = (unsigned*)(ws + off_hist1);
    unsigned* hist2 = (unsigned*)(ws + off_hist2);
    int* ctrl    = (int*)(ws + off_ctrl);
    float* gamma = (float*)(ws + off_gamma);
    float* lacc  = (float*)(ws + off_lacc);
    unsigned* lcnt = (unsigned*)(ws + off_lacc + 32);
    float* sfg   = (float*)(ws + off_sfg);
    float* sbg   = (float*)(ws + off_sbg);
    float* invn  = (float*)(ws + off_inv);
    float* pT    = (float*)(ws + off_pT);
    int* ties    = (int*)(ws + off_ties);
    float* feats = (float*)(ws + off_feats);
    float* tief  = (float*)(ws + off_tief);
    float* G     = (float*)(ws + off_G);
    float* D0    = (float*)(ws + off_D0);
    float* beta  = (float*)(ws + off_beta);
    float* dotsF = (float*)(ws + off_dotsF);
    float* pfin  = (float*)(ws + off_pfin);

    hipMemsetAsync(ws, 0, zbytes, stream);
    k_init<<<256, 256, 0, stream>>>(fg, bg, pT);
    k_score<<<576, 256, 0, stream>>>(F, pT, M, sfg, sbg, invn, hist1);
    k_scan<<<2, 1024, 0, stream>>>(hist1, ctrl, 0);
    k_hist2<<<dim3(576, 2), 256, 0, stream>>>(sfg, sbg, ctrl, hist2);
    k_scan<<<2, 1024, 0, stream>>>(hist2, ctrl, 1);
    k_collect<<<dim3(576, 2), 256, 0, stream>>>(sfg, sbg, invn, F, ctrl, ties, feats, tief);
    k_prep<<<42, 256, 0, stream>>>(fg, bg, ctrl, ties, tief, feats, G, D0, beta);
    k_iter<<<2, 1024, 0, stream>>>(G, D0, gamma, beta, dotsF);
    k_recon<<<128, 256, 0, stream>>>(fg, bg, feats, gamma, beta, pfin, out);
    k_loss<<<128, 256, 0, stream>>>(feats, pfin, dotsF, lacc, lcnt, out);
}